// Round 2
// baseline (1329.056 us; speedup 1.0000x reference)
//
#include <hip/hip_runtime.h>

#define NT 64               // one wave per group
#define GMAXN 1536          // max group size (NMAX in reference)
#define EPT 48              // max edges per thread: ceil((2*1536-1)/64)
#define ZPT 24              // max nodes per thread: 1536/64
#define TVITERS 20
#define BMAX 4096

__device__ int g_off[BMAX];
__device__ int g_maxdeg;

__device__ __forceinline__ float waveSum(float v) {
  #pragma unroll
  for (int o = 1; o < 64; o <<= 1) v += __shfl_xor(v, o, 64);
  return v;
}
__device__ __forceinline__ float waveMax(float v) {
  #pragma unroll
  for (int o = 1; o < 64; o <<= 1) v = fmaxf(v, __shfl_xor(v, o, 64));
  return v;
}

// K1: exclusive scan of sizes -> g_off, zero g_maxdeg. One block.
__global__ __launch_bounds__(256) void k_scan(const int* __restrict__ sizes, int B) {
  __shared__ int part[256];
  int t = threadIdx.x;
  int per = (B + 255) / 256;
  int base = t * per;
  int acc = 0;
  for (int k = 0; k < per; ++k) {
    int i = base + k;
    if (i < B) acc += sizes[i];
  }
  part[t] = acc;
  __syncthreads();
  if (t == 0) {
    int run = 0;
    for (int i = 0; i < 256; ++i) { int tmp = part[i]; part[i] = run; run += tmp; }
    g_maxdeg = 0;
  }
  __syncthreads();
  int run = part[t];
  for (int k = 0; k < per; ++k) {
    int i = base + k;
    if (i < B) { g_off[i] = run; run += sizes[i]; }
  }
}

// K2: per-group max degree -> global atomicMax. Chain part analytic. One wave.
__global__ __launch_bounds__(NT) void k_deg(const int* __restrict__ sizes,
                                            const int* __restrict__ edges,
                                            int N, int B) {
  __shared__ int cnt[GMAXN];
  int g = blockIdx.x;
  int t = threadIdx.x;
  int s = sizes[g];
  int off = g_off[g];
  for (int i = t; i < s; i += NT)
    cnt[i] = 2 - (i == 0 ? 1 : 0) - (i == s - 1 ? 1 : 0);
  __syncthreads();
  const int* re = edges + 2 * ((N - B) + off);
  for (int e = t; e < s; e += NT) {
    atomicAdd(&cnt[re[2 * e] - off], 1);
    atomicAdd(&cnt[re[2 * e + 1] - off], 1);
  }
  __syncthreads();
  int m = 0;
  for (int i = t; i < s; i += NT) m = max(m, cnt[i]);
  #pragma unroll
  for (int o = 1; o < 64; o <<= 1) m = max(m, __shfl_xor(m, o, 64));
  if (t == 0) atomicMax(&g_maxdeg, m);
}

// K3: one wave per group. 20-iter TV prox (y in LDS, u + edges + x in VGPRs)
// + sparsemax via bisection, all reductions as wave shuffles (no barriers
// needed beyond trivial single-wave __syncthreads for LDS ordering).
__global__ __launch_bounds__(NT) void k_main(const float* __restrict__ x,
                                             const int* __restrict__ sizes,
                                             const int* __restrict__ edges,
                                             float* __restrict__ out,
                                             int N, int B) {
  __shared__ float yL[GMAXN];
  int g = blockIdx.x;
  int t = threadIdx.x;
  int s = sizes[g];
  int off = g_off[g];
  int Eloc = 2 * s - 1;
  int nchain = s - 1;
  const int* re = edges + 2 * ((N - B) + off);
  float step = 1.0f / (2.0f * (float)g_maxdeg);

  // Edge slots: packed endpoints + u, all in VGPRs (compile-time indices only).
  uint ab[EPT];
  float uu[EPT];
  #pragma unroll
  for (int k = 0; k < EPT; ++k) {
    int e = t + k * NT;
    uu[k] = 0.0f;
    uint pk = 0;
    if (e < Eloc) {
      int a, b;
      if (e < nchain) { a = e; b = e + 1; }           // chain edge, analytic
      else { int r = e - nchain; a = re[2 * r] - off; b = re[2 * r + 1] - off; }
      pk = (uint)a | ((uint)b << 16);
    }
    ab[k] = pk;
  }

  // Cache this thread's x values in registers; y1 = x.
  const float* xg = x + off;
  float xr[ZPT];
  #pragma unroll
  for (int k = 0; k < ZPT; ++k) {
    int i = t + k * NT;
    xr[k] = (i < s) ? xg[i] : 0.0f;
    if (i < s) yL[i] = xr[k];
  }
  __syncthreads();

  for (int it = 0; it < TVITERS; ++it) {
    // u <- clip(u + step*(y[a]-y[b]), -1, 1)
    #pragma unroll
    for (int k = 0; k < EPT; ++k) {
      int e = t + k * NT;
      if (e < Eloc) {
        int a = (int)(ab[k] & 0xFFFFu);
        int b = (int)(ab[k] >> 16);
        float nu = uu[k] + step * (yL[a] - yL[b]);
        uu[k] = fminf(1.0f, fmaxf(-1.0f, nu));
      }
    }
    __syncthreads();
    // y <- x
    #pragma unroll
    for (int k = 0; k < ZPT; ++k) {
      int i = t + k * NT;
      if (i < s) yL[i] = xr[k];
    }
    __syncthreads();
    // y <- x - dT(u)
    #pragma unroll
    for (int k = 0; k < EPT; ++k) {
      int e = t + k * NT;
      if (e < Eloc) {
        int a = (int)(ab[k] & 0xFFFFu);
        int b = (int)(ab[k] >> 16);
        atomicAdd(&yL[a], -uu[k]);
        atomicAdd(&yL[b], uu[k]);
      }
    }
    __syncthreads();
  }

  // Sparsemax on z = y (GAMMA = 1), z in registers.
  float zr[ZPT];
  #pragma unroll
  for (int k = 0; k < ZPT; ++k) {
    int i = t + k * NT;
    zr[k] = (i < s) ? yL[i] : -1e30f;
  }
  float m = -1e30f;
  #pragma unroll
  for (int k = 0; k < ZPT; ++k) m = fmaxf(m, zr[k]);
  m = waveMax(m);

  // tau* in [zmax-1, zmax): bisect f(tau) = sum(max(z-tau,0)) vs 1
  float lo = m - 1.0f, hi = m;
  for (int r = 0; r < 30; ++r) {
    float mid = 0.5f * (lo + hi);
    float f = 0.0f;
    #pragma unroll
    for (int k = 0; k < ZPT; ++k) f += fmaxf(zr[k] - mid, 0.0f);
    f = waveSum(f);
    if (f >= 1.0f) lo = mid; else hi = mid;
  }
  // exact refinement on identified support: tau = (sum_support z - 1)/k
  float cntf = 0.0f, S = 0.0f;
  #pragma unroll
  for (int k = 0; k < ZPT; ++k) {
    if (zr[k] > lo) { cntf += 1.0f; S += zr[k]; }
  }
  cntf = waveSum(cntf);
  S = waveSum(S);
  float tau = (S - 1.0f) / cntf;

  float sf = (float)s;
  float* og = out + off;
  #pragma unroll
  for (int k = 0; k < ZPT; ++k) {
    int i = t + k * NT;
    if (i < s) og[i] = fmaxf(zr[k] - tau, 0.0f) * sf;
  }
}

extern "C" void kernel_launch(void* const* d_in, const int* in_sizes, int n_in,
                              void* d_out, int out_size, void* d_ws, size_t ws_size,
                              hipStream_t stream) {
  const float* x = (const float*)d_in[0];
  const int* sizes = (const int*)d_in[1];
  const int* edges = (const int*)d_in[2];
  float* out = (float*)d_out;
  int N = in_sizes[0];
  int B = in_sizes[1];
  (void)d_ws; (void)ws_size; (void)n_in; (void)out_size;

  k_scan<<<1, 256, 0, stream>>>(sizes, B);
  k_deg<<<B, NT, 0, stream>>>(sizes, edges, N, B);
  k_main<<<B, NT, 0, stream>>>(x, sizes, edges, out, N, B);
}

// Round 3
// 240.840 us; speedup vs baseline: 5.5184x; 5.5184x over previous
//
#include <hip/hip_runtime.h>

#define NT 256
#define GMAXN 1536          // max group size (NMAX)
#define EPT 12              // ceil((2*1536-1)/256) edge slots per thread
#define ZPT 6               // 1536/256 node slots per thread
#define TVITERS 20
#define BISECT 22
#define BMAX 4096

__device__ int g_off[BMAX];
__device__ int g_maxdeg;

__device__ __forceinline__ float blockSum(float v, float* red) {
  #pragma unroll
  for (int o = 32; o > 0; o >>= 1) v += __shfl_down(v, o, 64);
  int t = threadIdx.x;
  if ((t & 63) == 0) red[t >> 6] = v;
  __syncthreads();
  float tot = (red[0] + red[1]) + (red[2] + red[3]);
  __syncthreads();
  return tot;
}
__device__ __forceinline__ float blockMax(float v, float* red) {
  #pragma unroll
  for (int o = 32; o > 0; o >>= 1) v = fmaxf(v, __shfl_down(v, o, 64));
  int t = threadIdx.x;
  if ((t & 63) == 0) red[t >> 6] = v;
  __syncthreads();
  float tot = fmaxf(fmaxf(red[0], red[1]), fmaxf(red[2], red[3]));
  __syncthreads();
  return tot;
}

// K1: exclusive scan of sizes -> g_off, zero g_maxdeg. One block.
__global__ __launch_bounds__(NT) void k_scan(const int* __restrict__ sizes, int B) {
  __shared__ int part[NT];
  int t = threadIdx.x;
  int per = (B + NT - 1) / NT;
  int base = t * per;
  int acc = 0;
  for (int k = 0; k < per; ++k) {
    int i = base + k;
    if (i < B) acc += sizes[i];
  }
  part[t] = acc;
  __syncthreads();
  if (t == 0) {
    int run = 0;
    for (int i = 0; i < NT; ++i) { int tmp = part[i]; part[i] = run; run += tmp; }
    g_maxdeg = 0;
  }
  __syncthreads();
  int run = part[t];
  for (int k = 0; k < per; ++k) {
    int i = base + k;
    if (i < B) { g_off[i] = run; run += sizes[i]; }
  }
}

// K2: per-group max degree -> global atomicMax. Chain part analytic.
__global__ __launch_bounds__(NT) void k_deg(const int* __restrict__ sizes,
                                            const int* __restrict__ edges,
                                            int N, int B) {
  __shared__ int cnt[GMAXN];
  __shared__ int wred[4];
  int g = blockIdx.x;
  int t = threadIdx.x;
  int s = sizes[g];
  int off = g_off[g];
  for (int i = t; i < s; i += NT)
    cnt[i] = 2 - (i == 0 ? 1 : 0) - (i == s - 1 ? 1 : 0);
  __syncthreads();
  const int2* re2 = (const int2*)(edges + 2 * ((N - B) + off));
  for (int j = t; j < s; j += NT) {
    int2 e = re2[j];
    atomicAdd(&cnt[e.x - off], 1);
    atomicAdd(&cnt[e.y - off], 1);
  }
  __syncthreads();
  int m = 0;
  for (int i = t; i < s; i += NT) m = max(m, cnt[i]);
  #pragma unroll
  for (int o = 32; o > 0; o >>= 1) m = max(m, __shfl_down(m, o, 64));
  if ((t & 63) == 0) wred[t >> 6] = m;
  __syncthreads();
  if (t == 0) {
    m = max(max(wred[0], wred[1]), max(wred[2], wred[3]));
    atomicMax(&g_maxdeg, m);
  }
}

// K3: per-group CSR build (once) + 20-iter TV with pure gather (no atomics,
// 2 barriers/iter) + sparsemax bisection. One 256-thread block per group.
__global__ __launch_bounds__(NT) void k_main(const float* __restrict__ x,
                                             const int* __restrict__ sizes,
                                             const int* __restrict__ edges,
                                             float* __restrict__ out,
                                             int N, int B) {
  __shared__ float yL[GMAXN];           // y values (aliased as int cnt[] in build)
  __shared__ float uE[2 * GMAXN];       // u per edge (aliased as int cur[] in build)
  __shared__ ushort offL[GMAXN + 1];    // CSR offsets (random incidences)
  __shared__ ushort ent[2 * GMAXN];     // CSR entries: (j<<1)|sign
  __shared__ float red[4];
  __shared__ int wtot[4];

  int g = blockIdx.x;
  int t = threadIdx.x;
  int s = sizes[g];
  int off = g_off[g];
  int Eloc = 2 * s - 1;
  int nchain = s - 1;
  const int2* re2 = (const int2*)(edges + 2 * ((N - B) + off));
  float step = 1.0f / (2.0f * (float)g_maxdeg);

  // ---- load edge endpoints (packed) into registers
  uint ab[EPT];
  #pragma unroll
  for (int k = 0; k < EPT; ++k) {
    int e = t + k * NT;
    uint pk = 0;
    if (e < Eloc) {
      int a, b;
      if (e < nchain) { a = e; b = e + 1; }
      else { int2 v = re2[e - nchain]; a = v.x - off; b = v.y - off; }
      pk = (uint)a | ((uint)b << 16);
    }
    ab[k] = pk;
  }
  // ---- load x into registers
  const float* xg = x + off;
  float xr[ZPT];
  #pragma unroll
  for (int k = 0; k < ZPT; ++k) {
    int i = t + k * NT;
    xr[k] = (i < s) ? xg[i] : 0.0f;
  }

  // ---- CSR build (random edges only), once
  int* cnt = (int*)yL;
  for (int i = t; i < s; i += NT) cnt[i] = 0;
  __syncthreads();
  #pragma unroll
  for (int k = 0; k < EPT; ++k) {
    int e = t + k * NT;
    if (e >= nchain && e < Eloc) {
      int a = (int)(ab[k] & 0xFFFFu);
      int b = (int)(ab[k] >> 16);
      atomicAdd(&cnt[a], 1);
      atomicAdd(&cnt[b], 1);
    }
  }
  __syncthreads();
  // block-wide exclusive scan of cnt[0..s) (chunked: thread t owns [t*6, t*6+6))
  int lane = t & 63, wid = t >> 6;
  int c[ZPT];
  int tot = 0;
  #pragma unroll
  for (int k = 0; k < ZPT; ++k) {
    int i = t * ZPT + k;
    int v = (i < s) ? cnt[i] : 0;
    c[k] = tot; tot += v;
  }
  int inc = tot;
  #pragma unroll
  for (int o = 1; o < 64; o <<= 1) {
    int n = __shfl_up(inc, o, 64);
    if (lane >= o) inc += n;
  }
  if (lane == 63) wtot[wid] = inc;
  __syncthreads();
  int wpre = 0;
  #pragma unroll
  for (int w = 0; w < 4; ++w) wpre += (w < wid) ? wtot[w] : 0;
  int basep = wpre + (inc - tot);
  int* cur = (int*)uE;
  #pragma unroll
  for (int k = 0; k < ZPT; ++k) {
    int i = t * ZPT + k;
    if (i < s) { int v = basep + c[k]; offL[i] = (ushort)v; cur[i] = v; }
  }
  if (t == 0) offL[s] = (ushort)(2 * s);
  __syncthreads();
  // fill entries
  #pragma unroll
  for (int k = 0; k < EPT; ++k) {
    int e = t + k * NT;
    if (e >= nchain && e < Eloc) {
      int j = e - nchain;
      int a = (int)(ab[k] & 0xFFFFu);
      int b = (int)(ab[k] >> 16);
      int p = atomicAdd(&cur[a], 1);
      ent[p] = (ushort)(j << 1);
      p = atomicAdd(&cur[b], 1);
      ent[p] = (ushort)((j << 1) | 1);
    }
  }
  __syncthreads();
  // ---- y init = x (u0 = 0); overwrites cnt
  #pragma unroll
  for (int k = 0; k < ZPT; ++k) {
    int i = t + k * NT;
    if (i < s) yL[i] = xr[k];
  }
  __syncthreads();

  // ---- TV iterations: A) edge-parallel u update (plain write), B) node gather
  float uReg[EPT];
  #pragma unroll
  for (int k = 0; k < EPT; ++k) uReg[k] = 0.0f;
  float zr[ZPT];

  for (int it = 0; it < TVITERS; ++it) {
    // Phase A: batched gathers of y, then u update + publish
    float ya[EPT], yb[EPT];
    #pragma unroll
    for (int k = 0; k < EPT; ++k) {
      int e = t + k * NT;
      if (e < Eloc) {
        ya[k] = yL[(int)(ab[k] & 0xFFFFu)];
        yb[k] = yL[(int)(ab[k] >> 16)];
      }
    }
    #pragma unroll
    for (int k = 0; k < EPT; ++k) {
      int e = t + k * NT;
      if (e < Eloc) {
        float nu = uReg[k] + step * (ya[k] - yb[k]);
        nu = fminf(1.0f, fmaxf(-1.0f, nu));
        uReg[k] = nu;
        uE[e] = nu;
      }
    }
    __syncthreads();
    // Phase B: node-parallel gather: y = x - dT(u)
    #pragma unroll
    for (int k = 0; k < ZPT; ++k) {
      int i = t + k * NT;
      if (i < s) {
        float y = xr[k];
        if (i > 0)      y += uE[i - 1];
        if (i < nchain) y -= uE[i];
        int p0 = offL[i], p1 = offL[i + 1];
        for (int p = p0; p < p1; ++p) {
          ushort en = ent[p];
          float uj = uE[nchain + (en >> 1)];
          y += (en & 1) ? uj : -uj;
        }
        zr[k] = y;
        yL[i] = y;
      } else {
        zr[k] = -1e30f;
      }
    }
    __syncthreads();
  }

  // ---- sparsemax on z = y (GAMMA=1), z already in registers (zr)
  float m = -1e30f;
  #pragma unroll
  for (int k = 0; k < ZPT; ++k) m = fmaxf(m, zr[k]);
  m = blockMax(m, red);

  float lo = m - 1.0f, hi = m;
  for (int r = 0; r < BISECT; ++r) {
    float mid = 0.5f * (lo + hi);
    float f = 0.0f;
    #pragma unroll
    for (int k = 0; k < ZPT; ++k) f += fmaxf(zr[k] - mid, 0.0f);
    f = blockSum(f, red);
    if (f >= 1.0f) lo = mid; else hi = mid;
  }
  float cntf = 0.0f, S = 0.0f;
  #pragma unroll
  for (int k = 0; k < ZPT; ++k) {
    if (zr[k] > lo) { cntf += 1.0f; S += zr[k]; }
  }
  cntf = blockSum(cntf, red);
  S = blockSum(S, red);
  float tau = (S - 1.0f) / cntf;

  float sf = (float)s;
  float* og = out + off;
  #pragma unroll
  for (int k = 0; k < ZPT; ++k) {
    int i = t + k * NT;
    if (i < s) og[i] = fmaxf(zr[k] - tau, 0.0f) * sf;
  }
}

extern "C" void kernel_launch(void* const* d_in, const int* in_sizes, int n_in,
                              void* d_out, int out_size, void* d_ws, size_t ws_size,
                              hipStream_t stream) {
  const float* x = (const float*)d_in[0];
  const int* sizes = (const int*)d_in[1];
  const int* edges = (const int*)d_in[2];
  float* out = (float*)d_out;
  int N = in_sizes[0];
  int B = in_sizes[1];
  (void)d_ws; (void)ws_size; (void)n_in; (void)out_size;

  k_scan<<<1, NT, 0, stream>>>(sizes, B);
  k_deg<<<B, NT, 0, stream>>>(sizes, edges, N, B);
  k_main<<<B, NT, 0, stream>>>(x, sizes, edges, out, N, B);
}